// Round 4
// baseline (230.752 us; speedup 1.0000x reference)
//
#include <hip/hip_runtime.h>
#include <hip/hip_bf16.h>

#define HW   56
#define CIN  64
#define OC   512
#define NPIX (HW * HW)   // 3136
#define PEL  ((size_t)8 * NPIX * OC)   // elements per q/k/v tensor

typedef unsigned short ushort_t;
typedef __attribute__((ext_vector_type(8))) short short8;
typedef __attribute__((ext_vector_type(4))) float floatx4;
typedef __attribute__((ext_vector_type(16))) float floatx16;

static __device__ __forceinline__ ushort_t f2bf(float f) {
  __hip_bfloat16 h = __float2bfloat16(f);
  return *(ushort_t*)&h;
}

#if __has_builtin(__builtin_amdgcn_exp2f)
#define EXP2F(x) __builtin_amdgcn_exp2f(x)
#else
#define EXP2F(x) exp2f(x)
#endif

// ---------------------------------------------------------------------------
// Prepass (merged): one kernel, 960 blocks x 256 thr, branch on blockIdx.x.
//  [0,448):  x NCHW fp32 -> xT [b][h][w][c] bf16
//  [448,832): W [oc][cin][3][3] -> Wb [tap][j][cin] bf16 (q,k rows permuted
//             j=c*8+n <- oc=n*64+c so conv stores are identity; v identity)
//  [832,960): Wu fp32 -> bf16 identity
// ---------------------------------------------------------------------------
__global__ __launch_bounds__(256)
void prep_kernel(const float* __restrict__ x, const float* __restrict__ W0,
                 const float* __restrict__ W1, const float* __restrict__ W2,
                 const float* __restrict__ Wu, ushort_t* __restrict__ xT,
                 ushort_t* __restrict__ Wb, ushort_t* __restrict__ WuP) {
  __shared__ ushort_t lx[CIN * HW];
  const int bid = blockIdx.x;
  const int tid = threadIdx.x;

  if (bid < 448) {
    const int h = bid % HW, b = bid / HW;
    for (int idx = tid; idx < CIN * HW; idx += 256) {
      int c = idx / HW, w = idx - c * HW;
      lx[idx] = f2bf(x[((size_t)(b * CIN + c) * HW + h) * HW + w]);
    }
    __syncthreads();
    ushort_t* dst = xT + ((size_t)(b * HW + h)) * HW * CIN;
    for (int i = tid; i < (CIN * HW) / 4; i += 256) {
      int e0 = i * 4;
      int w = e0 >> 6, c0 = e0 & 63;
      ushort4 o;
      o.x = lx[(c0 + 0) * HW + w];
      o.y = lx[(c0 + 1) * HW + w];
      o.z = lx[(c0 + 2) * HW + w];
      o.w = lx[(c0 + 3) * HW + w];
      ((ushort4*)dst)[i] = o;
    }
  } else if (bid < 832) {
    const int u = bid - 448;           // [0,384)
    const int sel = u / 128;
    const int j = (u % 128) * 4 + (tid >> 6);
    const int cin = tid & 63;
    const float* W = sel == 0 ? W0 : (sel == 1 ? W1 : W2);
    ushort_t* Ds = Wb + (size_t)sel * 9 * OC * CIN;
    const int src = (sel < 2) ? ((j & 7) * 64 + (j >> 3)) : j;
    #pragma unroll
    for (int tap = 0; tap < 9; ++tap)
      Ds[((size_t)tap * OC + j) * CIN + cin] = f2bf(W[(size_t)src * 576 + cin * 9 + tap]);
  } else {
    const int el = (bid - 832) * 256 + tid;   // [0, 32768)
    WuP[el] = f2bf(Wu[el]);
  }
}

// ---------------------------------------------------------------------------
// Kernel 1: q/k/v 3x3 conv via MFMA 32x32x16 bf16 implicit GEMM.
//
// r16 = r13 structure + r15's A-read halving, regression causes removed.
// r15 post-mortem: halving LDS reads was right (conflicts 580K->290K) but it
// (a) cut B-prefetch to 1 step (~64cy) < L2 latency (~200cy) -> per-step
// stall, and (b) moved s back to grid -> 3x staging + 2.6 residency rounds.
// r16 keeps BOTH r13 wins and the partition:
//   - s-merged: 448 blocks (one round), x staged ONCE, 27-tap linear weight
//     stream, FULL-TAP B ping-pong (8 loads issued 192-256 MFMA-cycles
//     before use).
//   - 2x2 wave partition: wave (th=wv>>1, oh=wv&1) owns m-tiles
//     th?{4,5,6}:{0..3} x 2 oc-groups (64 oc).  Each A ds_read feeds 2
//     MFMAs -> device LDS reads halve vs r13.
//   - regs: 128 acc + 64 B + ~30 addr ~= 225 < 256 -> 2 waves/SIMD intact.
// ROW-swizzle sw(r)=2*((-r)&3) unchanged (bank-balanced at write & read).
// Spill tripwire: WRITE_SIZE must stay ~76MB.
// ---------------------------------------------------------------------------
#define XLS 72             // padded cin stride in x LDS tile (bf16 units)
#define XROW (58 * XLS)

__global__ __launch_bounds__(256, 2)
void conv3x3_qkv(const ushort_t* __restrict__ xT, const ushort_t* __restrict__ Wb,
                 ushort_t* __restrict__ yq) {
  __shared__ __align__(16) ushort_t xl[6 * XROW];   // 50112 B

  const int tid  = threadIdx.x;
  const int lane = tid & 63;
  const int wv   = tid >> 6;
  const int g    = blockIdx.x;        // [0,14): 4-row group
  const int ob   = blockIdx.y;        // [0,4): 128-oc slice
  const int b    = blockIdx.z;        // [0,8): batch
  const int h0   = g * 4;
  const int l31  = lane & 31;
  const int khi  = lane >> 5;         // 0/1: K-half

  const int th    = wv >> 1;          // 0: tiles 0..3, 1: tiles 4..6
  const int oh    = wv & 1;           // oc-group pair base = oh*2
  const int tbase = th * 4;

  // A per local m-tile: pixel p = (tbase+t)*32 + l31 within the 4-row strip
  int rowcol[4], rowv[4];
  #pragma unroll
  for (int t = 0; t < 4; ++t) {
    int p = (tbase + t) * 32 + l31;
    int row = p / HW, ww = p - row * HW;
    rowcol[t] = (row * 58 + ww) * XLS;   // t=3 of th=1 unused (guarded)
    rowv[t] = row;
  }

  // B base: oc = ob*128 + oh*64 + l31 (+32 for 2nd group), k-els khi*8..+7.
  // Per-lane 16B global loads; Wb (1.77MB) is L2-resident; wave pairs
  // (wv0,wv2) and (wv1,wv3) issue identical addresses -> L1 broadcast.
  const ushort_t* wb0 = Wb + ((size_t)(ob * 128 + oh * 64 + l31)) * CIN + khi * 8;

  // ---- stage x rows h0-1 .. h0+4 ONCE with row swizzle; zero halos
  for (int r = 0; r < 6; ++r) {
    int gh = h0 - 1 + r;
    const int sw = 2 * ((-r) & 3);
    if (gh >= 0 && gh < HW) {
      const uint4* src = (const uint4*)(xT + ((size_t)(b * HW + gh) * HW) * CIN);
      for (int idx = tid; idx < 448; idx += 256) {
        int w = idx >> 3, c8 = idx & 7;
        int col = 1 + w;
        int p8 = (c8 + sw) & 7;
        *(uint4*)&xl[(r * 58 + col) * XLS + p8 * 8] = src[idx];
      }
      if (tid < 16) {
        int col = (tid >> 3) ? 57 : 0, c8 = tid & 7;
        int p8 = (c8 + sw) & 7;
        *(uint4*)&xl[(r * 58 + col) * XLS + p8 * 8] = (uint4){0, 0, 0, 0};
      }
    } else {
      for (int idx = tid; idx < 464; idx += 256) {
        int col = idx >> 3, c8 = idx & 7;
        int p8 = (c8 + sw) & 7;
        *(uint4*)&xl[(r * 58 + col) * XLS + p8 * 8] = (uint4){0, 0, 0, 0};
      }
    }
  }

  // Full-tap weight ping-pong: BfA = current tap (2 groups x 4 ck), BfB = next
  short8 BfA[2][4], BfB[2][4];
  #pragma unroll
  for (int gq = 0; gq < 2; ++gq)
    #pragma unroll
    for (int ck = 0; ck < 4; ++ck)
      BfA[gq][ck] = *(const short8*)(wb0 + gq * (32 * CIN) + ck * 16);

  __syncthreads();

  // ---- s-loop over q/k/v; tap loop fully unrolled, s rolled (indices stay
  // compile-time constant; code ~1x).
  #pragma unroll 1
  for (int s = 0; s < 3; ++s) {
    floatx16 acc[4][2];
    #pragma unroll
    for (int t = 0; t < 4; ++t) {
      acc[t][0] = (floatx16)(0.0f);
      acc[t][1] = (floatx16)(0.0f);
    }

    #pragma unroll
    for (int tap = 0; tap < 9; ++tap) {
      const int wtap = s * 9 + tap;           // s dynamic, tap constant
      if (wtap < 26) {
        #pragma unroll
        for (int gq = 0; gq < 2; ++gq)
          #pragma unroll
          for (int ck = 0; ck < 4; ++ck)
            BfB[gq][ck] = *(const short8*)(wb0 + (size_t)(wtap + 1) * (OC * CIN) +
                                           gq * (32 * CIN) + ck * 16);
      }
      const int kh = tap / 3, kw = tap - kh * 3;
      #pragma unroll
      for (int ck = 0; ck < 4; ++ck) {
        #pragma unroll
        for (int t = 0; t < 4; ++t) {
          if (tbase + t < 7) {                 // wave-uniform guard
            int chunk = (khi + 2 * ((-(rowv[t] + kh)) & 3) + 2 * ck) & 7;
            short8 af = *(const short8*)&xl[rowcol[t] + (kh * 58 + kw) * XLS + chunk * 8];
            acc[t][0] = __builtin_amdgcn_mfma_f32_32x32x16_bf16(af, BfA[0][ck], acc[t][0], 0, 0, 0);
            acc[t][1] = __builtin_amdgcn_mfma_f32_32x32x16_bf16(af, BfA[1][ck], acc[t][1], 0, 0, 0);
          }
        }
      }
      #pragma unroll
      for (int gq = 0; gq < 2; ++gq)
        #pragma unroll
        for (int ck = 0; ck < 4; ++ck) BfA[gq][ck] = BfB[gq][ck];
    }

    // ---- epilogue for tensor s: D col=oc=l31 (contiguous), row=px
    ushort_t* y = yq + (size_t)s * PEL;
    const int ocb = ob * 128 + oh * 64 + l31;
    #pragma unroll
    for (int t = 0; t < 4; ++t) {
      if (tbase + t < 7) {
        #pragma unroll
        for (int i = 0; i < 16; ++i) {
          int p = (tbase + t) * 32 + (i & 3) + 8 * (i >> 2) + 4 * khi;
          int row = p / HW, ww = p - row * HW;
          size_t pb = ((size_t)((b * HW + h0 + row) * HW + ww)) * OC;
          y[pb + ocb]      = f2bf(acc[t][0][i]);
          y[pb + ocb + 32] = f2bf(acc[t][1][i]);
        }
      }
    }
  }
}

// ---------------------------------------------------------------------------
// Kernel 2: MFMA channel-attention + 1x1 conv + ReLU.
// r14 softmax diet (kernel was latency-bound: Mfma 6.5%, VALU 37%, HBM 9%):
//  (a) NO max-subtraction.  S = sum_8 q*k: sigma_S ~ 4; exp2 overflow needs
//      ~500 sigma -> impossible.  Softmax shift-invariant -> identical.
//  (b) exp fused: e = exp2(S * (scale*log2e)).
//  (c) deferred normalization: P stored UNNORMALIZED; inv[nt] applied at
//      T-write (same-lane mapping, no shuffle).  Tree-sum depth 4.
// ---------------------------------------------------------------------------
#define PST  72    // P LDS row stride (bf16 el): 144B rows, 16B-aligned
#define A2ST 520   // a2 stride: 16B-aligned, 2-way banks

__global__ __launch_bounds__(256, 3)
void attn_kernel(const ushort_t* __restrict__ q, const ushort_t* __restrict__ k,
                 const ushort_t* __restrict__ v, const ushort_t* __restrict__ WuP,
                 float* __restrict__ out) {
  __shared__ __align__(16) ushort_t Pl[4][64 * PST];   // per-wave P[qc][kc] bf16
  __shared__ __align__(16) ushort_t a2[16 * A2ST];     // attended [pix][c*8+n]

  const int tid  = threadIdx.x;
  const int lane = tid & 63;
  const int wv   = tid >> 6;
  const int l15  = lane & 15;
  const int quad = lane >> 4;
  const int p0   = blockIdx.x * 16;
  const int b    = blockIdx.y;
  const size_t ibase = ((size_t)b * NPIX + p0) * 512;

  ushort_t* Pw = &Pl[wv][0];
  // scale2 = (1/sqrt(512)) * log2(e)
  const float scale2 = 0.063758723f;

  auto loadpix = [&](int plocal, short8 qf[4], short8 kf[4], short8 vf[2]) {
    const ushort_t* qp = q + ibase + (size_t)plocal * 512;
    const ushort_t* kp = k + ibase + (size_t)plocal * 512;
    const ushort_t* vp = v + ibase + (size_t)plocal * 512;
    #pragma unroll
    for (int nt = 0; nt < 4; ++nt)
      qf[nt] = *(const short8*)(qp + (nt * 16 + l15) * 8);
    #pragma unroll
    for (int mt = 0; mt < 4; ++mt) {
      kf[mt] = (short8){0, 0, 0, 0, 0, 0, 0, 0};
      if (quad == 0) kf[mt] = *(const short8*)(kp + (mt * 16 + l15) * 8);
    }
    #pragma unroll
    for (int ck = 0; ck < 2; ++ck)
      vf[ck] = *(const short8*)(vp + (l15 & 7) * 64 + ck * 32 + quad * 8);
  };

  short8 qf[4], kf[4], vf[2];
  loadpix(wv * 4, qf, kf, vf);

  #pragma unroll
  for (int i = 0; i < 4; ++i) {
    const int plocal = wv * 4 + i;
    short8 qn[4], kn[4], vn[2];
    if (i < 3) loadpix(plocal + 1, qn, kn, vn);

    // ---- S^T[kc][qc] = k . q^T  (contraction n=8, padded in K=32 via A=0)
    floatx4 S[4][4];
    #pragma unroll
    for (int mt = 0; mt < 4; ++mt)
      #pragma unroll
      for (int nt = 0; nt < 4; ++nt) S[mt][nt] = (floatx4){0.f, 0.f, 0.f, 0.f};
    #pragma unroll
    for (int mt = 0; mt < 4; ++mt)
      #pragma unroll
      for (int nt = 0; nt < 4; ++nt)
        S[mt][nt] = __builtin_amdgcn_mfma_f32_16x16x32_bf16(kf[mt], qf[nt], S[mt][nt], 0, 0, 0);

    // ---- exp + tree-sum (no max-sub); P written UNNORMALIZED
    float inv[4];
    #pragma unroll
    for (int nt = 0; nt < 4; ++nt) {
      float e[4][4];
      #pragma unroll
      for (int mt = 0; mt < 4; ++mt)
        #pragma unroll
        for (int r = 0; r < 4; ++r)
          e[mt][r] = EXP2F(S[mt][nt][r] * scale2);
      float sm[4];
      #pragma unroll
      for (int mt = 0; mt < 4; ++mt)
        sm[mt] = (e[mt][0] + e[mt][1]) + (e[mt][2] + e[mt][3]);
      float sum = (sm[0] + sm[1]) + (sm[2] + sm[3]);
      sum += __shfl_xor(sum, 16);
      sum += __shfl_xor(sum, 32);
      inv[nt] = __builtin_amdgcn_rcpf(sum);
      #pragma unroll
      for (int mt = 0; mt < 4; ++mt) {
        ushort4 w4;
        w4.x = f2bf(e[mt][0]);
        w4.y = f2bf(e[mt][1]);
        w4.z = f2bf(e[mt][2]);
        w4.w = f2bf(e[mt][3]);
        *(ushort4*)&Pw[(nt * 16 + l15) * PST + mt * 16 + quad * 4] = w4;
      }
    }

    // ---- attended^T[n][qc] = v^T . P^T   (M=n pad 16, N=qc 64, K=kc 64)
    floatx4 T[4];
    #pragma unroll
    for (int nt = 0; nt < 4; ++nt) T[nt] = (floatx4){0.f, 0.f, 0.f, 0.f};
    #pragma unroll
    for (int ck = 0; ck < 2; ++ck) {
      #pragma unroll
      for (int nt = 0; nt < 4; ++nt) {
        short8 pf = *(const short8*)&Pw[(nt * 16 + l15) * PST + ck * 32 + quad * 8];
        T[nt] = __builtin_amdgcn_mfma_f32_16x16x32_bf16(vf[ck], pf, T[nt], 0, 0, 0);
      }
    }
    if (quad < 2) {
      #pragma unroll
      for (int nt = 0; nt < 4; ++nt) {
        ushort4 w4;
        w4.x = f2bf(T[nt][0] * inv[nt]);
        w4.y = f2bf(T[nt][1] * inv[nt]);
        w4.z = f2bf(T[nt][2] * inv[nt]);
        w4.w = f2bf(T[nt][3] * inv[nt]);
        *(ushort4*)&a2[plocal * A2ST + (nt * 16 + l15) * 8 + quad * 4] = w4;
      }
    }

    if (i < 3) {
      #pragma unroll
      for (int z = 0; z < 4; ++z) { qf[z] = qn[z]; kf[z] = kn[z]; }
      vf[0] = vn[0];
      vf[1] = vn[1];
    }
  }
  __syncthreads();

  // ---- out GEMM: M=co(wave's 16), N=16 pixels, K=512
  floatx4 O = (floatx4){0.f, 0.f, 0.f, 0.f};
  #pragma unroll
  for (int ck = 0; ck < 16; ++ck) {
    short8 aw = *(const short8*)(WuP + (size_t)(wv * 16 + l15) * 512 + ck * 32 + quad * 8);
    short8 bw = *(const short8*)&a2[l15 * A2ST + ck * 32 + quad * 8];
    O = __builtin_amdgcn_mfma_f32_16x16x32_bf16(aw, bw, O, 0, 0, 0);
  }
  #pragma unroll
  for (int r = 0; r < 4; ++r) {
    int co = wv * 16 + quad * 4 + r;
    out[((size_t)b * 64 + co) * NPIX + p0 + l15] = fmaxf(O[r], 0.f);
  }
}

// ---------------------------------------------------------------------------
extern "C" void kernel_launch(void* const* d_in, const int* in_sizes, int n_in,
                              void* d_out, int out_size, void* d_ws, size_t ws_size,
                              hipStream_t stream) {
  const float* x  = (const float*)d_in[0];
  const float* Wq = (const float*)d_in[1];
  const float* Wk = (const float*)d_in[2];
  const float* Wv = (const float*)d_in[3];
  const float* Wu = (const float*)d_in[4];
  float* out = (float*)d_out;

  const size_t xT_elems = (size_t)8 * NPIX * CIN;
  const size_t w_elems  = (size_t)9 * OC * CIN;
  const size_t wu_elems = (size_t)64 * 512;
  ushort_t* xT  = (ushort_t*)d_ws;
  ushort_t* Wb  = xT + xT_elems;          // 27 taps: q(9) k(9) v(9)
  ushort_t* WuP = Wb + 3 * w_elems;
  ushort_t* q   = WuP + wu_elems;
  ushort_t* k   = q + PEL;
  ushort_t* v   = k + PEL;

  prep_kernel<<<960, 256, 0, stream>>>(x, Wq, Wk, Wv, Wu, xT, Wb, WuP);

  dim3 cgrid(14, 4, 8);  // (4-row groups, 128-oc slices, batch)
  conv3x3_qkv<<<cgrid, 256, 0, stream>>>(xT, Wb, q);

  attn_kernel<<<dim3(NPIX / 16, 8), 256, 0, stream>>>(q, k, v, WuP, out);
}

// Round 5
// 148.534 us; speedup vs baseline: 1.5535x; 1.5535x over previous
//
#include <hip/hip_runtime.h>
#include <hip/hip_bf16.h>

#define HW   56
#define CIN  64
#define OC   512
#define NPIX (HW * HW)   // 3136
#define PEL  ((size_t)8 * NPIX * OC)   // elements per q/k/v tensor

typedef unsigned short ushort_t;
typedef __attribute__((ext_vector_type(8))) short short8;
typedef __attribute__((ext_vector_type(4))) float floatx4;
typedef __attribute__((ext_vector_type(16))) float floatx16;

static __device__ __forceinline__ ushort_t f2bf(float f) {
  __hip_bfloat16 h = __float2bfloat16(f);
  return *(ushort_t*)&h;
}

#if __has_builtin(__builtin_amdgcn_exp2f)
#define EXP2F(x) __builtin_amdgcn_exp2f(x)
#else
#define EXP2F(x) exp2f(x)
#endif

// ---------------------------------------------------------------------------
// Prepass (merged): one kernel, 960 blocks x 256 thr, branch on blockIdx.x.
//  [0,448):  x NCHW fp32 -> xT [b][h][w][c] bf16
//  [448,832): W [oc][cin][3][3] -> Wb [tap][j][cin] bf16 (q,k rows permuted
//             j=c*8+n <- oc=n*64+c so conv stores are identity; v identity)
//  [832,960): Wu fp32 -> bf16 identity
// ---------------------------------------------------------------------------
__global__ __launch_bounds__(256)
void prep_kernel(const float* __restrict__ x, const float* __restrict__ W0,
                 const float* __restrict__ W1, const float* __restrict__ W2,
                 const float* __restrict__ Wu, ushort_t* __restrict__ xT,
                 ushort_t* __restrict__ Wb, ushort_t* __restrict__ WuP) {
  __shared__ ushort_t lx[CIN * HW];
  const int bid = blockIdx.x;
  const int tid = threadIdx.x;

  if (bid < 448) {
    const int h = bid % HW, b = bid / HW;
    for (int idx = tid; idx < CIN * HW; idx += 256) {
      int c = idx / HW, w = idx - c * HW;
      lx[idx] = f2bf(x[((size_t)(b * CIN + c) * HW + h) * HW + w]);
    }
    __syncthreads();
    ushort_t* dst = xT + ((size_t)(b * HW + h)) * HW * CIN;
    for (int i = tid; i < (CIN * HW) / 4; i += 256) {
      int e0 = i * 4;
      int w = e0 >> 6, c0 = e0 & 63;
      ushort4 o;
      o.x = lx[(c0 + 0) * HW + w];
      o.y = lx[(c0 + 1) * HW + w];
      o.z = lx[(c0 + 2) * HW + w];
      o.w = lx[(c0 + 3) * HW + w];
      ((ushort4*)dst)[i] = o;
    }
  } else if (bid < 832) {
    const int u = bid - 448;           // [0,384)
    const int sel = u / 128;
    const int j = (u % 128) * 4 + (tid >> 6);
    const int cin = tid & 63;
    const float* W = sel == 0 ? W0 : (sel == 1 ? W1 : W2);
    ushort_t* Ds = Wb + (size_t)sel * 9 * OC * CIN;
    const int src = (sel < 2) ? ((j & 7) * 64 + (j >> 3)) : j;
    #pragma unroll
    for (int tap = 0; tap < 9; ++tap)
      Ds[((size_t)tap * OC + j) * CIN + cin] = f2bf(W[(size_t)src * 576 + cin * 9 + tap]);
  } else {
    const int el = (bid - 832) * 256 + tid;   // [0, 32768)
    WuP[el] = f2bf(Wu[el]);
  }
}

// ---------------------------------------------------------------------------
// Kernel 1: q/k/v 3x3 conv via MFMA 32x32x16 bf16 implicit GEMM.
// Block: 4 rows (224 px = 7 m-tiles of 32) x 128 oc; wave = 32-oc slice.
//
// r17 = REVERT to proven r13 (57.6-62.8 us, no spill) after r15/r16 showed
// the 2x2 wave partition cannot fit registers: shallow B-prefetch stalls
// (r15: MfmaUtil 28->18), full-tap prefetch spills (r16: WRITE 135MB,
// FETCH 97MB scratch traffic).  Partition line abandoned.
//
// r13: (a) s-merge — x staged ONCE, s-loop q/k/v reuses acc regs; grid
// 14x4x8 = 448 blocks (one residency round, no tail).  Linear 27-tap weight
// stream prefetched one tap ahead (BfA/BfB ping-pong).
// (b) ROW-based LDS swizzle sw(r) = 2*((-r)&3): bank group of a 16B chunk =
// (2r + col + chunk) mod 8; chunk = logical + sw(r) makes it == col + const
// == pixel + const (mod 8) [56 == 0 mod 8] -> balanced banks at every lane
// window including m-tile row crossings.  Same swizzle at write and read.
// r17 adds ONLY: s_setprio(1)/(0) around the MFMA cluster (T5).  This
// K-loop has zero barriers -> waves drift to different phases -> scheduler
// has roles to arbitrate (m191 regime, not m190's lockstep null).
// ---------------------------------------------------------------------------
#define XLS 72             // padded cin stride in x LDS tile (bf16 units)
#define XROW (58 * XLS)

__global__ __launch_bounds__(256, 2)
void conv3x3_qkv(const ushort_t* __restrict__ xT, const ushort_t* __restrict__ Wb,
                 ushort_t* __restrict__ yq) {
  __shared__ __align__(16) ushort_t xl[6 * XROW];   // 50112 B

  const int tid  = threadIdx.x;
  const int lane = tid & 63;
  const int wv   = tid >> 6;
  const int g    = blockIdx.x;        // [0,14): 4-row group
  const int ob   = blockIdx.y;        // [0,4): 128-oc slice
  const int b    = blockIdx.z;        // [0,8): batch
  const int h0   = g * 4;
  const int l31  = lane & 31;
  const int khi  = lane >> 5;         // 0/1: K-half

  // A per m-tile: pixel p = t*32 + l31 within the 4-row strip
  int rowcol[7], rowv[7];
  #pragma unroll
  for (int t = 0; t < 7; ++t) {
    int p = t * 32 + l31;
    int row = p / HW, ww = p - row * HW;
    rowcol[t] = (row * 58 + ww) * XLS;
    rowv[t] = row;
  }

  // B base: oc = ob*128 + wv*32 + l31, k els khi*8..+7; tap stream is linear
  const ushort_t* wb0 = Wb + ((size_t)(ob * 128 + wv * 32 + l31)) * CIN + khi * 8;

  // ---- stage x rows h0-1 .. h0+4 ONCE with row swizzle; zero halos
  for (int r = 0; r < 6; ++r) {
    int gh = h0 - 1 + r;
    const int sw = 2 * ((-r) & 3);
    if (gh >= 0 && gh < HW) {
      const uint4* src = (const uint4*)(xT + ((size_t)(b * HW + gh) * HW) * CIN);
      for (int idx = tid; idx < 448; idx += 256) {
        int w = idx >> 3, c8 = idx & 7;
        int col = 1 + w;
        int p8 = (c8 + sw) & 7;
        *(uint4*)&xl[(r * 58 + col) * XLS + p8 * 8] = src[idx];
      }
      if (tid < 16) {
        int col = (tid >> 3) ? 57 : 0, c8 = tid & 7;
        int p8 = (c8 + sw) & 7;
        *(uint4*)&xl[(r * 58 + col) * XLS + p8 * 8] = (uint4){0, 0, 0, 0};
      }
    } else {
      for (int idx = tid; idx < 464; idx += 256) {
        int col = idx >> 3, c8 = idx & 7;
        int p8 = (c8 + sw) & 7;
        *(uint4*)&xl[(r * 58 + col) * XLS + p8 * 8] = (uint4){0, 0, 0, 0};
      }
    }
  }

  // Weight ping-pong: BfA = current tap, BfB = prefetched next tap
  short8 BfA[4], BfB[4];
  #pragma unroll
  for (int ck = 0; ck < 4; ++ck)
    BfA[ck] = *(const short8*)(wb0 + ck * 16);

  __syncthreads();

  // ---- s-loop over q/k/v; tap loop fully unrolled, s kept rolled so code
  // stays ~1x (all reg-array indices remain compile-time constant).
  #pragma unroll 1
  for (int s = 0; s < 3; ++s) {
    floatx16 acc[7];
    #pragma unroll
    for (int t = 0; t < 7; ++t) acc[t] = (floatx16)(0.0f);

    #pragma unroll
    for (int tap = 0; tap < 9; ++tap) {
      const int wtap = s * 9 + tap;           // s dynamic, tap constant
      if (wtap < 26) {
        #pragma unroll
        for (int ck = 0; ck < 4; ++ck)
          BfB[ck] = *(const short8*)(wb0 + (size_t)(wtap + 1) * (OC * CIN) + ck * 16);
      }
      const int kh = tap / 3, kw = tap - kh * 3;
      int baddr[7], b8[7];
      #pragma unroll
      for (int t = 0; t < 7; ++t) {
        baddr[t] = rowcol[t] + (kh * 58 + kw) * XLS;
        b8[t] = khi + 2 * ((-(rowv[t] + kh)) & 3);
      }
      __builtin_amdgcn_s_setprio(1);
      #pragma unroll
      for (int ck = 0; ck < 4; ++ck) {
        #pragma unroll
        for (int t = 0; t < 7; ++t) {
          int chunk = (b8[t] + 2 * ck) & 7;
          short8 af = *(const short8*)&xl[baddr[t] + chunk * 8];
          acc[t] = __builtin_amdgcn_mfma_f32_32x32x16_bf16(af, BfA[ck], acc[t], 0, 0, 0);
        }
      }
      __builtin_amdgcn_s_setprio(0);
      #pragma unroll
      for (int ck = 0; ck < 4; ++ck) BfA[ck] = BfB[ck];
    }

    // ---- epilogue for tensor s: D col=oc=l31 (contiguous), row=px
    ushort_t* y = yq + (size_t)s * PEL;
    const int oc = ob * 128 + wv * 32 + l31;
    #pragma unroll
    for (int t = 0; t < 7; ++t) {
      #pragma unroll
      for (int i = 0; i < 16; ++i) {
        int p = t * 32 + (i & 3) + 8 * (i >> 2) + 4 * khi;
        int row = p / HW, ww = p - row * HW;
        size_t pb = ((size_t)((b * HW + h0 + row) * HW + ww)) * OC;
        y[pb + oc] = f2bf(acc[t][i]);
      }
    }
  }
}

// ---------------------------------------------------------------------------
// Kernel 2: MFMA channel-attention + 1x1 conv + ReLU.
// r14 softmax diet (kernel was latency-bound: Mfma 6.5%, VALU 37%, HBM 9%):
//  (a) NO max-subtraction.  S = sum_8 q*k: sigma_S ~ 4; exp2 overflow needs
//      ~500 sigma -> impossible.  Softmax shift-invariant -> identical.
//  (b) exp fused: e = exp2(S * (scale*log2e)).
//  (c) deferred normalization: P stored UNNORMALIZED; inv[nt] applied at
//      T-write (same-lane mapping, no shuffle).  Tree-sum depth 4.
// ---------------------------------------------------------------------------
#define PST  72    // P LDS row stride (bf16 el): 144B rows, 16B-aligned
#define A2ST 520   // a2 stride: 16B-aligned, 2-way banks

__global__ __launch_bounds__(256, 3)
void attn_kernel(const ushort_t* __restrict__ q, const ushort_t* __restrict__ k,
                 const ushort_t* __restrict__ v, const ushort_t* __restrict__ WuP,
                 float* __restrict__ out) {
  __shared__ __align__(16) ushort_t Pl[4][64 * PST];   // per-wave P[qc][kc] bf16
  __shared__ __align__(16) ushort_t a2[16 * A2ST];     // attended [pix][c*8+n]

  const int tid  = threadIdx.x;
  const int lane = tid & 63;
  const int wv   = tid >> 6;
  const int l15  = lane & 15;
  const int quad = lane >> 4;
  const int p0   = blockIdx.x * 16;
  const int b    = blockIdx.y;
  const size_t ibase = ((size_t)b * NPIX + p0) * 512;

  ushort_t* Pw = &Pl[wv][0];
  // scale2 = (1/sqrt(512)) * log2(e)
  const float scale2 = 0.063758723f;

  auto loadpix = [&](int plocal, short8 qf[4], short8 kf[4], short8 vf[2]) {
    const ushort_t* qp = q + ibase + (size_t)plocal * 512;
    const ushort_t* kp = k + ibase + (size_t)plocal * 512;
    const ushort_t* vp = v + ibase + (size_t)plocal * 512;
    #pragma unroll
    for (int nt = 0; nt < 4; ++nt)
      qf[nt] = *(const short8*)(qp + (nt * 16 + l15) * 8);
    #pragma unroll
    for (int mt = 0; mt < 4; ++mt) {
      kf[mt] = (short8){0, 0, 0, 0, 0, 0, 0, 0};
      if (quad == 0) kf[mt] = *(const short8*)(kp + (mt * 16 + l15) * 8);
    }
    #pragma unroll
    for (int ck = 0; ck < 2; ++ck)
      vf[ck] = *(const short8*)(vp + (l15 & 7) * 64 + ck * 32 + quad * 8);
  };

  short8 qf[4], kf[4], vf[2];
  loadpix(wv * 4, qf, kf, vf);

  #pragma unroll
  for (int i = 0; i < 4; ++i) {
    const int plocal = wv * 4 + i;
    short8 qn[4], kn[4], vn[2];
    if (i < 3) loadpix(plocal + 1, qn, kn, vn);

    // ---- S^T[kc][qc] = k . q^T  (contraction n=8, padded in K=32 via A=0)
    floatx4 S[4][4];
    #pragma unroll
    for (int mt = 0; mt < 4; ++mt)
      #pragma unroll
      for (int nt = 0; nt < 4; ++nt) S[mt][nt] = (floatx4){0.f, 0.f, 0.f, 0.f};
    #pragma unroll
    for (int mt = 0; mt < 4; ++mt)
      #pragma unroll
      for (int nt = 0; nt < 4; ++nt)
        S[mt][nt] = __builtin_amdgcn_mfma_f32_16x16x32_bf16(kf[mt], qf[nt], S[mt][nt], 0, 0, 0);

    // ---- exp + tree-sum (no max-sub); P written UNNORMALIZED
    float inv[4];
    #pragma unroll
    for (int nt = 0; nt < 4; ++nt) {
      float e[4][4];
      #pragma unroll
      for (int mt = 0; mt < 4; ++mt)
        #pragma unroll
        for (int r = 0; r < 4; ++r)
          e[mt][r] = EXP2F(S[mt][nt][r] * scale2);
      float sm[4];
      #pragma unroll
      for (int mt = 0; mt < 4; ++mt)
        sm[mt] = (e[mt][0] + e[mt][1]) + (e[mt][2] + e[mt][3]);
      float sum = (sm[0] + sm[1]) + (sm[2] + sm[3]);
      sum += __shfl_xor(sum, 16);
      sum += __shfl_xor(sum, 32);
      inv[nt] = __builtin_amdgcn_rcpf(sum);
      #pragma unroll
      for (int mt = 0; mt < 4; ++mt) {
        ushort4 w4;
        w4.x = f2bf(e[mt][0]);
        w4.y = f2bf(e[mt][1]);
        w4.z = f2bf(e[mt][2]);
        w4.w = f2bf(e[mt][3]);
        *(ushort4*)&Pw[(nt * 16 + l15) * PST + mt * 16 + quad * 4] = w4;
      }
    }

    // ---- attended^T[n][qc] = v^T . P^T   (M=n pad 16, N=qc 64, K=kc 64)
    floatx4 T[4];
    #pragma unroll
    for (int nt = 0; nt < 4; ++nt) T[nt] = (floatx4){0.f, 0.f, 0.f, 0.f};
    #pragma unroll
    for (int ck = 0; ck < 2; ++ck) {
      #pragma unroll
      for (int nt = 0; nt < 4; ++nt) {
        short8 pf = *(const short8*)&Pw[(nt * 16 + l15) * PST + ck * 32 + quad * 8];
        T[nt] = __builtin_amdgcn_mfma_f32_16x16x32_bf16(vf[ck], pf, T[nt], 0, 0, 0);
      }
    }
    if (quad < 2) {
      #pragma unroll
      for (int nt = 0; nt < 4; ++nt) {
        ushort4 w4;
        w4.x = f2bf(T[nt][0] * inv[nt]);
        w4.y = f2bf(T[nt][1] * inv[nt]);
        w4.z = f2bf(T[nt][2] * inv[nt]);
        w4.w = f2bf(T[nt][3] * inv[nt]);
        *(ushort4*)&a2[plocal * A2ST + (nt * 16 + l15) * 8 + quad * 4] = w4;
      }
    }

    if (i < 3) {
      #pragma unroll
      for (int z = 0; z < 4; ++z) { qf[z] = qn[z]; kf[z] = kn[z]; }
      vf[0] = vn[0];
      vf[1] = vn[1];
    }
  }
  __syncthreads();

  // ---- out GEMM: M=co(wave's 16), N=16 pixels, K=512
  floatx4 O = (floatx4){0.f, 0.f, 0.f, 0.f};
  #pragma unroll
  for (int ck = 0; ck < 16; ++ck) {
    short8 aw = *(const short8*)(WuP + (size_t)(wv * 16 + l15) * 512 + ck * 32 + quad * 8);
    short8 bw = *(const short8*)&a2[l15 * A2ST + ck * 32 + quad * 8];
    O = __builtin_amdgcn_mfma_f32_16x16x32_bf16(aw, bw, O, 0, 0, 0);
  }
  #pragma unroll
  for (int r = 0; r < 4; ++r) {
    int co = wv * 16 + quad * 4 + r;
    out[((size_t)b * 64 + co) * NPIX + p0 + l15] = fmaxf(O[r], 0.f);
  }
}

// ---------------------------------------------------------------------------
extern "C" void kernel_launch(void* const* d_in, const int* in_sizes, int n_in,
                              void* d_out, int out_size, void* d_ws, size_t ws_size,
                              hipStream_t stream) {
  const float* x  = (const float*)d_in[0];
  const float* Wq = (const float*)d_in[1];
  const float* Wk = (const float*)d_in[2];
  const float* Wv = (const float*)d_in[3];
  const float* Wu = (const float*)d_in[4];
  float* out = (float*)d_out;

  const size_t xT_elems = (size_t)8 * NPIX * CIN;
  const size_t w_elems  = (size_t)9 * OC * CIN;
  const size_t wu_elems = (size_t)64 * 512;
  ushort_t* xT  = (ushort_t*)d_ws;
  ushort_t* Wb  = xT + xT_elems;          // 27 taps: q(9) k(9) v(9)
  ushort_t* WuP = Wb + 3 * w_elems;
  ushort_t* q   = WuP + wu_elems;
  ushort_t* k   = q + PEL;
  ushort_t* v   = k + PEL;

  prep_kernel<<<960, 256, 0, stream>>>(x, Wq, Wk, Wv, Wu, xT, Wb, WuP);

  dim3 cgrid(14, 4, 8);  // (4-row groups, 128-oc slices, batch)
  conv3x3_qkv<<<cgrid, 256, 0, stream>>>(xT, Wb, q);

  attn_kernel<<<dim3(NPIX / 16, 8), 256, 0, stream>>>(q, k, v, WuP, out);
}